// Round 6
// baseline (133.001 us; speedup 1.0000x reference)
//
#include <hip/hip_runtime.h>
#include <hip/hip_bf16.h>

#define D_MODEL 256
#define NHEADS 4
#define DHEAD 64
#define BATCH 4
#define TSEQ 2048
#define CHUNK 64
#define NCHUNK (TSEQ / CHUNK)   // 32
#define NTOK (BATCH * TSEQ)     // 8192
#define NBH (BATCH * NHEADS)    // 16
#define EPSV 1e-6f
#define LSTRF 68                // fp32 LDS row stride (verified)
#define PQ 36                   // packed-bf16 LDS row stride in uints (144B)

typedef __bf16 bf16x8 __attribute__((ext_vector_type(8)));
typedef float f32x4 __attribute__((ext_vector_type(4)));
typedef unsigned short us8 __attribute__((ext_vector_type(8)));

__device__ __forceinline__ float elu1(float a) {
    return a > 0.0f ? a + 1.0f : __expf(a);
}

__device__ __forceinline__ unsigned short f2bf(float f) {
    __hip_bfloat16 h = __float2bfloat16(f);   // RNE
    return __builtin_bit_cast(unsigned short, h);
}

__device__ __forceinline__ float bf2f(unsigned short u) {
    return __bfloat162float(__builtin_bit_cast(__hip_bfloat16, u));
}

// unpack a dword holding 2 bf16 (lo,hi) into 2 fp32 — 2 VALU ops
__device__ __forceinline__ void unpack2(unsigned int u, float& lo, float& hi) {
    lo = __builtin_bit_cast(float, u << 16);
    hi = __builtin_bit_cast(float, u & 0xFFFF0000u);
}

// Build a bf16x8 MFMA fragment from 8 consecutive fp32 (16B-aligned).
__device__ __forceinline__ bf16x8 frag8(const float* p) {
    const float4 x = *reinterpret_cast<const float4*>(p);
    const float4 y = *reinterpret_cast<const float4*>(p + 4);
    us8 u;
    u[0] = f2bf(x.x); u[1] = f2bf(x.y); u[2] = f2bf(x.z); u[3] = f2bf(x.w);
    u[4] = f2bf(y.x); u[5] = f2bf(y.y); u[6] = f2bf(y.z); u[7] = f2bf(y.w);
    return __builtin_bit_cast(bf16x8, u);
}

// pack 8 fp32 (array) -> bf16x8
__device__ __forceinline__ bf16x8 pack8(const float* p) {
    us8 u;
#pragma unroll
    for (int j = 0; j < 8; ++j) u[j] = f2bf(p[j]);
    return __builtin_bit_cast(bf16x8, u);
}

// async global->LDS, 16B per lane; lds ptr must be wave-uniform base.
__device__ __forceinline__ void gld_lds16(const void* g, void* l) {
    __builtin_amdgcn_global_load_lds(
        (const __attribute__((address_space(1))) void*)g,
        (__attribute__((address_space(3))) void*)l, 16, 0, 0);
}

// ---------------------------------------------------------------------------
// qkv GEMM with FUSED fp32->bf16 conversion of x and W^T (convert kernel
// eliminated). Full-K staging (R5-verified layout/read side), one barrier.
// A: reg-staged from fp32 x (coalesced rows). B: W^T gather (coalesced
// 64-wide row segments, L2-resident). 64x64 tile, grid 128x12.
// ---------------------------------------------------------------------------
__global__ __launch_bounds__(256) void qkv_kernel(
    const float* __restrict__ x,
    const float* __restrict__ Wq, const float* __restrict__ Wk,
    const float* __restrict__ Wv,
    const float* __restrict__ bq, const float* __restrict__ bk,
    const float* __restrict__ bv,
    unsigned short* __restrict__ Qb, unsigned short* __restrict__ Kb,
    unsigned short* __restrict__ Vb)
{
    __shared__ __align__(16) unsigned short As[64 * 256];   // 32 KB
    __shared__ __align__(16) unsigned short Bs[64 * 256];   // 32 KB
    const int tid = threadIdx.x;
    const int wave = tid >> 6, lane = tid & 63;
    const int la = lane & 15, q = lane >> 4;

    const int ntile = blockIdx.x % 12, mtile = blockIdx.x / 12;
    const int m0 = mtile * 64;
    const int which = ntile >> 2;            // 0:Q 1:K 2:V (block-uniform)
    const int wcol0 = (ntile & 3) * 64;      // column offset within W
    const float* W    = which == 0 ? Wq : which == 1 ? Wk : Wv;
    const float* bias = which == 0 ? bq : which == 1 ? bk : bv;
    unsigned short* Out = which == 0 ? Qb : which == 1 ? Kb : Vb;
    const int act = (which < 2);

    // ---- stage A: x[m0+m][k] fp32 -> bf16, swizzled slot g^(m&7) ----
#pragma unroll
    for (int i = 0; i < 8; ++i) {
        const int task = i * 256 + tid;      // 2048 tasks: (m, 8k-group g)
        const int m = task >> 5, g = task & 31;
        const float* src = &x[(size_t)(m0 + m) * D_MODEL + g * 8];
        const float4 a = *reinterpret_cast<const float4*>(src);
        const float4 b = *reinterpret_cast<const float4*>(src + 4);
        us8 u;
        u[0] = f2bf(a.x); u[1] = f2bf(a.y); u[2] = f2bf(a.z); u[3] = f2bf(a.w);
        u[4] = f2bf(b.x); u[5] = f2bf(b.y); u[6] = f2bf(b.z); u[7] = f2bf(b.w);
        *reinterpret_cast<us8*>(&As[m * 256 + ((g ^ (m & 7)) << 3)]) = u;
    }
    // ---- stage B: Bs[n][k] = W[k][wcol0+n] fp32 -> bf16 (transpose) ----
    // lanes read consecutive n at fixed k (coalesced 256B row segments).
#pragma unroll
    for (int i = 0; i < 8; ++i) {
        const int task = i * 256 + tid;      // (8k-group g, n)
        const int n = task & 63, g = (task >> 6) + i * 4 * 0 + (i * 4) * 0;
        const int gg = i * 4 + (task >> 6 & 3);   // g in [0,32): 4 per iter
        const int k0 = gg * 8;
        us8 u;
#pragma unroll
        for (int j = 0; j < 8; ++j)
            u[j] = f2bf(W[(size_t)(k0 + j) * D_MODEL + wcol0 + n]);
        *reinterpret_cast<us8*>(&Bs[n * 256 + ((gg ^ (n & 7)) << 3)]) = u;
        (void)g;
    }
    __syncthreads();

    // ---- MFMA loop: identical to R5-verified full-K body ----
    f32x4 acc[4];
#pragma unroll
    for (int i = 0; i < 4; ++i) acc[i] = (f32x4){0.f, 0.f, 0.f, 0.f};

#pragma unroll
    for (int kh = 0; kh < 8; ++kh) {
        const int gl = kh * 4 + q;
        const int m = wave * 16 + la;
        const bf16x8 af = *reinterpret_cast<const bf16x8*>(
            &As[m * 256 + ((gl ^ (m & 7)) << 3)]);
#pragma unroll
        for (int ni = 0; ni < 4; ++ni) {
            const int n = ni * 16 + la;
            const bf16x8 bf = *reinterpret_cast<const bf16x8*>(
                &Bs[n * 256 + ((gl ^ (n & 7)) << 3)]);
            acc[ni] = __builtin_amdgcn_mfma_f32_16x16x32_bf16(
                af, bf, acc[ni], 0, 0, 0);
        }
    }

    // C/D layout: col=lane&15, row=(lane>>4)*4+reg
#pragma unroll
    for (int ni = 0; ni < 4; ++ni) {
        const int row = m0 + wave * 16 + q * 4;
        const int cl = wcol0 + ni * 16 + la;      // column within Q/K/V
        const float bv2 = bias[cl];
#pragma unroll
        for (int r = 0; r < 4; ++r) {
            float v = acc[ni][r] + bv2;
            if (act) v = elu1(v);
            Out[(size_t)(row + r) * D_MODEL + cl] = f2bf(v);
        }
    }
}

// ---------------------------------------------------------------------------
// output GEMM with FUSED Wo^T conversion. A = Ob (bf16) via verified
// gld_lds16 full-K staging; B = Wo^T gather fp32->bf16. fp32 out + bias.
// ---------------------------------------------------------------------------
__global__ __launch_bounds__(256) void ogemm_kernel(
    const unsigned short* __restrict__ Ob, const float* __restrict__ Wo,
    const float* __restrict__ bo, float* __restrict__ out)
{
    __shared__ __align__(16) unsigned short As[64 * 256];   // 32 KB
    __shared__ __align__(16) unsigned short Bs[64 * 256];   // 32 KB
    const int tid = threadIdx.x;
    const int wave = tid >> 6, lane = tid & 63;
    const int la = lane & 15, q = lane >> 4;

    const int ntile = blockIdx.x & 3, mtile = blockIdx.x >> 2;
    const int m0 = mtile * 64, n0 = ntile * 64;

    const unsigned short* Ab = Ob + (size_t)m0 * D_MODEL;

    // A: verified async staging (R5)
#pragma unroll
    for (int i = 0; i < 8; ++i) {
        const int bslot = i * 256 + wave * 64;   // wave-uniform base
        const int slot = bslot + lane;
        const int m = slot >> 5, s = slot & 31;
        const int g = s ^ (m & 7);
        gld_lds16(Ab + (size_t)m * D_MODEL + g * 8, &As[bslot * 8]);
    }
    // B: Wo^T gather (coalesced rows)
#pragma unroll
    for (int i = 0; i < 8; ++i) {
        const int task = i * 256 + tid;
        const int n = task & 63;
        const int gg = i * 4 + (task >> 6 & 3);
        const int k0 = gg * 8;
        us8 u;
#pragma unroll
        for (int j = 0; j < 8; ++j)
            u[j] = f2bf(Wo[(size_t)(k0 + j) * D_MODEL + n0 + n]);
        *reinterpret_cast<us8*>(&Bs[n * 256 + ((gg ^ (n & 7)) << 3)]) = u;
    }
    __syncthreads();

    f32x4 acc[4];
#pragma unroll
    for (int i = 0; i < 4; ++i) acc[i] = (f32x4){0.f, 0.f, 0.f, 0.f};

#pragma unroll
    for (int kh = 0; kh < 8; ++kh) {
        const int gl = kh * 4 + q;
        const int m = wave * 16 + la;
        const bf16x8 af = *reinterpret_cast<const bf16x8*>(
            &As[m * 256 + ((gl ^ (m & 7)) << 3)]);
#pragma unroll
        for (int ni = 0; ni < 4; ++ni) {
            const int n = ni * 16 + la;
            const bf16x8 bf = *reinterpret_cast<const bf16x8*>(
                &Bs[n * 256 + ((gl ^ (n & 7)) << 3)]);
            acc[ni] = __builtin_amdgcn_mfma_f32_16x16x32_bf16(
                af, bf, acc[ni], 0, 0, 0);
        }
    }

#pragma unroll
    for (int ni = 0; ni < 4; ++ni) {
        const int row = m0 + wave * 16 + q * 4;
        const int col = n0 + ni * 16 + la;
        const float bv2 = bo[col];
#pragma unroll
        for (int r = 0; r < 4; ++r)
            out[(size_t)(row + r) * D_MODEL + col] = acc[ni][r] + bv2;
    }
}

// ---------------------------------------------------------------------------
// chunksum (R17-verified packed staging) — unchanged: raw per-chunk P (bf16)
// and raw per-chunk Z sums (fp32).
// ---------------------------------------------------------------------------
__global__ __launch_bounds__(256) void chunksum_kernel(
    const unsigned short* __restrict__ Kb, const unsigned short* __restrict__ Vb,
    unsigned short* __restrict__ Pb16, float* __restrict__ Zc)
{
    __shared__ __align__(16) unsigned int Ktp[DHEAD * PQ];  // [d][t/2]
    __shared__ __align__(16) unsigned int Vtp[DHEAD * PQ];  // [m][t/2]
    const int tid = threadIdx.x;
    const int c  = blockIdx.x % NCHUNK;
    const int bh = blockIdx.x / NCHUNK;
    const int b = bh / NHEADS, h = bh % NHEADS;
    const size_t gbase = ((size_t)(b * TSEQ + c * CHUNK)) * D_MODEL + h * DHEAD;

    {
        const int sp = tid & 31, mg = tid >> 5;
        const int e0 = mg * 8;
        const uint4 k0 = *reinterpret_cast<const uint4*>(
            &Kb[gbase + (size_t)(2 * sp) * D_MODEL + e0]);
        const uint4 k1 = *reinterpret_cast<const uint4*>(
            &Kb[gbase + (size_t)(2 * sp + 1) * D_MODEL + e0]);
        const uint4 v0 = *reinterpret_cast<const uint4*>(
            &Vb[gbase + (size_t)(2 * sp) * D_MODEL + e0]);
        const uint4 v1 = *reinterpret_cast<const uint4*>(
            &Vb[gbase + (size_t)(2 * sp + 1) * D_MODEL + e0]);
        const unsigned short* ke = reinterpret_cast<const unsigned short*>(&k0);
        const unsigned short* ko2 = reinterpret_cast<const unsigned short*>(&k1);
        const unsigned short* ve = reinterpret_cast<const unsigned short*>(&v0);
        const unsigned short* vo = reinterpret_cast<const unsigned short*>(&v1);
#pragma unroll
        for (int j = 0; j < 8; ++j) {
            Ktp[(e0 + j) * PQ + sp] =
                (unsigned int)ke[j] | ((unsigned int)ko2[j] << 16);
            Vtp[(e0 + j) * PQ + sp] =
                (unsigned int)ve[j] | ((unsigned int)vo[j] << 16);
        }
    }
    __syncthreads();

    const int wave = tid >> 6, lane = tid & 63;
    const int la = lane & 15, q = lane >> 4;
    const int wm = (wave >> 1) * 32, wn = (wave & 1) * 32;   // m rows, d cols

    f32x4 acc[2][2];
#pragma unroll
    for (int i = 0; i < 2; ++i)
#pragma unroll
        for (int j = 0; j < 2; ++j) acc[i][j] = (f32x4){0.f, 0.f, 0.f, 0.f};

#pragma unroll
    for (int ks = 0; ks < 2; ++ks) {
        const int ku = ks * 16 + q * 4;                      // uint offset (k=t)
        const bf16x8 a0  = __builtin_bit_cast(bf16x8,
            *reinterpret_cast<const uint4*>(&Vtp[(wm + la) * PQ + ku]));
        const bf16x8 a1  = __builtin_bit_cast(bf16x8,
            *reinterpret_cast<const uint4*>(&Vtp[(wm + 16 + la) * PQ + ku]));
        const bf16x8 bb0 = __builtin_bit_cast(bf16x8,
            *reinterpret_cast<const uint4*>(&Ktp[(wn + la) * PQ + ku]));
        const bf16x8 bb1 = __builtin_bit_cast(bf16x8,
            *reinterpret_cast<const uint4*>(&Ktp[(wn + 16 + la) * PQ + ku]));
        acc[0][0] = __builtin_amdgcn_mfma_f32_16x16x32_bf16(a0, bb0, acc[0][0], 0, 0, 0);
        acc[0][1] = __builtin_amdgcn_mfma_f32_16x16x32_bf16(a0, bb1, acc[0][1], 0, 0, 0);
        acc[1][0] = __builtin_amdgcn_mfma_f32_16x16x32_bf16(a1, bb0, acc[1][0], 0, 0, 0);
        acc[1][1] = __builtin_amdgcn_mfma_f32_16x16x32_bf16(a1, bb1, acc[1][1], 0, 0, 0);
    }

    unsigned short* Pb = Pb16 + (size_t)blockIdx.x * (DHEAD * DHEAD);
#pragma unroll
    for (int mi = 0; mi < 2; ++mi)
#pragma unroll
        for (int ni = 0; ni < 2; ++ni) {
            const int row = wm + mi * 16 + q * 4;   // m
            const int col = wn + ni * 16 + la;      // d
#pragma unroll
            for (int r = 0; r < 4; ++r)
                Pb[(row + r) * DHEAD + col] = f2bf(acc[mi][ni][r]);
        }

    if (tid < DHEAD) {
        float z = 0.f;
        for (int tt = 0; tt < 32; ++tt) {
            float lo, hi;
            unpack2(Ktp[tid * PQ + tt], lo, hi);
            z += lo;
            z += hi;
        }
        Zc[(size_t)blockIdx.x * DHEAD + tid] = z;
    }
}

// ---------------------------------------------------------------------------
// chunkout with FUSED prefix: each block accumulates its own exclusive-prefix
// S fragments (fp32, ascending-chunk order = bit-identical to old prefix
// kernel) from raw P, and Z_prev from raw Zc. prefix kernel + Sb eliminated.
// ---------------------------------------------------------------------------
__global__ __launch_bounds__(256) void chunkout_kernel(
    const unsigned short* __restrict__ Qb, const unsigned short* __restrict__ Kb,
    const unsigned short* __restrict__ Vb,
    const unsigned short* __restrict__ Pb16, const float* __restrict__ Zc,
    unsigned short* __restrict__ Ob)
{
    __shared__ __align__(16) unsigned int Qp[CHUNK * PQ];   // packed [t][d/2]
    __shared__ __align__(16) unsigned int Kp[CHUNK * PQ];   // packed [s][d/2]
    __shared__ __align__(16) unsigned int Vtp[DHEAD * PQ];  // packed [m][s/2]
    __shared__ __align__(16) float At[CHUNK * LSTRF];       // fp32 [t][s]
    __shared__ float zsh[DHEAD];
    __shared__ float dnm[CHUNK];

    const int tid = threadIdx.x;
    const int c  = blockIdx.x % NCHUNK;
    const int bh = blockIdx.x / NCHUNK;
    const int b = bh / NHEADS, h = bh % NHEADS;
    const size_t gbase = ((size_t)(b * TSEQ + c * CHUNK)) * D_MODEL + h * DHEAD;

    const int wave = tid >> 6, lane = tid & 63;
    const int la = lane & 15, q = lane >> 4;
    const int wt = (wave >> 1) * 32, wn = (wave & 1) * 32;

    // stage Q,K: straight packed 16B copies (no conversion)
#pragma unroll
    for (int i = 0; i < 2; ++i) {
        const int idx = i * 256 + tid;           // 0..511
        const int t = idx >> 3, e4 = (idx & 7) * 4;   // uint offset in row
        const uint4 qv = *reinterpret_cast<const uint4*>(
            &Qb[gbase + (size_t)t * D_MODEL + e4 * 2]);
        const uint4 kv = *reinterpret_cast<const uint4*>(
            &Kb[gbase + (size_t)t * D_MODEL + e4 * 2]);
        *reinterpret_cast<uint4*>(&Qp[t * PQ + e4]) = qv;
        *reinterpret_cast<uint4*>(&Kp[t * PQ + e4]) = kv;
    }
    // stage V transposed, packed along s: thread = (s-pair, 8 m's)
    {
        const int sp = tid & 31, mg = tid >> 5;
        const int m0 = mg * 8;
        const uint4 v0 = *reinterpret_cast<const uint4*>(
            &Vb[gbase + (size_t)(2 * sp) * D_MODEL + m0]);
        const uint4 v1 = *reinterpret_cast<const uint4*>(
            &Vb[gbase + (size_t)(2 * sp + 1) * D_MODEL + m0]);
        const unsigned short* ev = reinterpret_cast<const unsigned short*>(&v0);
        const unsigned short* ov = reinterpret_cast<const unsigned short*>(&v1);
#pragma unroll
        for (int j = 0; j < 8; ++j)
            Vtp[(m0 + j) * PQ + sp] =
                (unsigned int)ev[j] | ((unsigned int)ov[j] << 16);
    }
    // Z_prev: exclusive prefix of raw Zc (ascending order, fp32)
    if (tid < DHEAD) {
        float zv = 0.f;
        for (int cc = 0; cc < c; ++cc)
            zv += Zc[((size_t)bh * NCHUNK + cc) * DHEAD + tid];
        zsh[tid] = zv;
    }

    // ---- fused prefix: accumulate S_prev fragments this thread needs ----
    // rows r0=wn+la, r1=wn+16+la; per ks: 8 elems at ko=ks*32+q*8
    float sacc[2][2][8];
#pragma unroll
    for (int ri = 0; ri < 2; ++ri)
#pragma unroll
        for (int ks = 0; ks < 2; ++ks)
#pragma unroll
            for (int j = 0; j < 8; ++j) sacc[ri][ks][j] = 0.f;
    {
        const unsigned short* Pbase =
            Pb16 + (size_t)bh * NCHUNK * (DHEAD * DHEAD);
        const int r0 = wn + la, r1 = wn + 16 + la;
        for (int cc = 0; cc < c; ++cc) {
            const unsigned short* Pc = Pbase + (size_t)cc * (DHEAD * DHEAD);
#pragma unroll
            for (int ri = 0; ri < 2; ++ri) {
                const int row = ri ? r1 : r0;
#pragma unroll
                for (int ks = 0; ks < 2; ++ks) {
                    const int ko = ks * 32 + q * 8;
                    const uint4 v = *reinterpret_cast<const uint4*>(
                        &Pc[row * DHEAD + ko]);
                    const unsigned int* w = reinterpret_cast<const unsigned int*>(&v);
#pragma unroll
                    for (int d = 0; d < 4; ++d) {
                        float lo, hi;
                        unpack2(w[d], lo, hi);
                        sacc[ri][ks][2 * d]     += lo;
                        sacc[ri][ks][2 * d + 1] += hi;
                    }
                }
            }
        }
    }
    bf16x8 sfrag[2][2];
#pragma unroll
    for (int ri = 0; ri < 2; ++ri)
#pragma unroll
        for (int ks = 0; ks < 2; ++ks)
            sfrag[ri][ks] = pack8(sacc[ri][ks]);

    __syncthreads();

    // phase 1: A = Q K^T
    f32x4 acc[2][2];
#pragma unroll
    for (int i = 0; i < 2; ++i)
#pragma unroll
        for (int j = 0; j < 2; ++j) acc[i][j] = (f32x4){0.f, 0.f, 0.f, 0.f};
#pragma unroll
    for (int ks = 0; ks < 2; ++ks) {
        const int ku = ks * 16 + q * 4;                      // uint offset (k=d)
        const bf16x8 a0  = __builtin_bit_cast(bf16x8,
            *reinterpret_cast<const uint4*>(&Qp[(wt + la) * PQ + ku]));
        const bf16x8 a1  = __builtin_bit_cast(bf16x8,
            *reinterpret_cast<const uint4*>(&Qp[(wt + 16 + la) * PQ + ku]));
        const bf16x8 bb0 = __builtin_bit_cast(bf16x8,
            *reinterpret_cast<const uint4*>(&Kp[(wn + la) * PQ + ku]));
        const bf16x8 bb1 = __builtin_bit_cast(bf16x8,
            *reinterpret_cast<const uint4*>(&Kp[(wn + 16 + la) * PQ + ku]));
        acc[0][0] = __builtin_amdgcn_mfma_f32_16x16x32_bf16(a0, bb0, acc[0][0], 0, 0, 0);
        acc[0][1] = __builtin_amdgcn_mfma_f32_16x16x32_bf16(a0, bb1, acc[0][1], 0, 0, 0);
        acc[1][0] = __builtin_amdgcn_mfma_f32_16x16x32_bf16(a1, bb0, acc[1][0], 0, 0, 0);
        acc[1][1] = __builtin_amdgcn_mfma_f32_16x16x32_bf16(a1, bb1, acc[1][1], 0, 0, 0);
    }
#pragma unroll
    for (int mi = 0; mi < 2; ++mi)
#pragma unroll
        for (int ni = 0; ni < 2; ++ni) {
            const int t0 = wt + mi * 16 + q * 4;
            const int s  = wn + ni * 16 + la;
#pragma unroll
            for (int r = 0; r < 4; ++r)
                At[(t0 + r) * LSTRF + s] = (s <= t0 + r) ? acc[mi][ni][r] : 0.f;
        }
    __syncthreads();

    // phase 2: denom[t] = rowsum(A) + Q . Z_prev + eps  (Q via unpack2)
    if (tid < CHUNK) {
        float dv = 0.f;
        for (int s = 0; s < CHUNK; ++s) dv += At[tid * LSTRF + s];
        for (int dd = 0; dd < 32; ++dd) {
            float lo, hi;
            unpack2(Qp[tid * PQ + dd], lo, hi);
            dv = fmaf(lo, zsh[2 * dd], dv);
            dv = fmaf(hi, zsh[2 * dd + 1], dv);
        }
        dnm[tid] = dv + EPSV;
    }
    __syncthreads();

    // phase 3: O = Q @ S_prev + A @ V   (S_prev from fused-prefix registers)
    f32x4 o[2][2];
#pragma unroll
    for (int i = 0; i < 2; ++i)
#pragma unroll
        for (int j = 0; j < 2; ++j) o[i][j] = (f32x4){0.f, 0.f, 0.f, 0.f};
#pragma unroll
    for (int ks = 0; ks < 2; ++ks) {
        const int ku = ks * 16 + q * 4;                      // uint offset (k=d)
        const bf16x8 a0  = __builtin_bit_cast(bf16x8,
            *reinterpret_cast<const uint4*>(&Qp[(wt + la) * PQ + ku]));
        const bf16x8 a1  = __builtin_bit_cast(bf16x8,
            *reinterpret_cast<const uint4*>(&Qp[(wt + 16 + la) * PQ + ku]));
        const bf16x8 bb0 = sfrag[0][ks];
        const bf16x8 bb1 = sfrag[1][ks];
        o[0][0] = __builtin_amdgcn_mfma_f32_16x16x32_bf16(a0, bb0, o[0][0], 0, 0, 0);
        o[0][1] = __builtin_amdgcn_mfma_f32_16x16x32_bf16(a0, bb1, o[0][1], 0, 0, 0);
        o[1][0] = __builtin_amdgcn_mfma_f32_16x16x32_bf16(a1, bb0, o[1][0], 0, 0, 0);
        o[1][1] = __builtin_amdgcn_mfma_f32_16x16x32_bf16(a1, bb1, o[1][1], 0, 0, 0);
    }
#pragma unroll
    for (int ks = 0; ks < 2; ++ks) {
        const int ku = ks * 16 + q * 4;                      // uint offset (k=s)
        const int ko = ks * 32 + q * 8;
        const bf16x8 a0  = frag8(&At[(wt + la) * LSTRF + ko]);
        const bf16x8 a1  = frag8(&At[(wt + 16 + la) * LSTRF + ko]);
        const bf16x8 bb0 = __builtin_bit_cast(bf16x8,
            *reinterpret_cast<const uint4*>(&Vtp[(wn + la) * PQ + ku]));
        const bf16x8 bb1 = __builtin_bit_cast(bf16x8,
            *reinterpret_cast<const uint4*>(&Vtp[(wn + 16 + la) * PQ + ku]));
        o[0][0] = __builtin_amdgcn_mfma_f32_16x16x32_bf16(a0, bb0, o[0][0], 0, 0, 0);
        o[0][1] = __builtin_amdgcn_mfma_f32_16x16x32_bf16(a0, bb1, o[0][1], 0, 0, 0);
        o[1][0] = __builtin_amdgcn_mfma_f32_16x16x32_bf16(a1, bb0, o[1][0], 0, 0, 0);
        o[1][1] = __builtin_amdgcn_mfma_f32_16x16x32_bf16(a1, bb1, o[1][1], 0, 0, 0);
    }

    // epilogue: divide + bf16 scalar stores (verified class)
#pragma unroll
    for (int mi = 0; mi < 2; ++mi)
#pragma unroll
        for (int ni = 0; ni < 2; ++ni) {
            const int t0 = wt + mi * 16 + q * 4;
            const int m  = wn + ni * 16 + la;
#pragma unroll
            for (int r = 0; r < 4; ++r) {
                const float v = o[mi][ni][r] / dnm[t0 + r];
                Ob[gbase + (size_t)(t0 + r) * D_MODEL + m] = f2bf(v);
            }
        }
}

extern "C" void kernel_launch(void* const* d_in, const int* in_sizes, int n_in,
                              void* d_out, int out_size, void* d_ws, size_t ws_size,
                              hipStream_t stream)
{
    const float* x  = (const float*)d_in[0];
    const float* Wq = (const float*)d_in[1];
    const float* bq = (const float*)d_in[2];
    const float* Wk = (const float*)d_in[3];
    const float* bk = (const float*)d_in[4];
    const float* Wv = (const float*)d_in[5];
    const float* bv = (const float*)d_in[6];
    const float* Wo = (const float*)d_in[7];
    const float* bo = (const float*)d_in[8];
    float* out = (float*)d_out;

    const size_t NE = (size_t)NTOK * D_MODEL;               // 2M elems
    const size_t PE = (size_t)NBH * NCHUNK * DHEAD * DHEAD; // 2M elems
    unsigned short* Qb   = (unsigned short*)d_ws;           // 2M bf16
    unsigned short* Kb   = Qb + NE;                         // 2M
    unsigned short* Vb   = Kb + NE;                         // 2M
    unsigned short* Ob   = Vb + NE;                         // 2M
    unsigned short* Pb16 = Ob + NE;                         // 2M bf16
    float* Z = (float*)(Pb16 + PE);                         // 16*32*64 f32

    qkv_kernel<<<(NTOK / 64) * 12, 256, 0, stream>>>(
        x, Wq, Wk, Wv, bq, bk, bv, Qb, Kb, Vb);
    chunksum_kernel<<<NBH * NCHUNK, 256, 0, stream>>>(Kb, Vb, Pb16, Z);
    chunkout_kernel<<<NBH * NCHUNK, 256, 0, stream>>>(Qb, Kb, Vb, Pb16, Z, Ob);
    ogemm_kernel<<<(NTOK / 64) * 4, 256, 0, stream>>>(Ob, Wo, bo, out);
}

// Round 9
// 104.608 us; speedup vs baseline: 1.2714x; 1.2714x over previous
//
#include <hip/hip_runtime.h>
#include <hip/hip_bf16.h>

#define D_MODEL 256
#define NHEADS 4
#define DHEAD 64
#define BATCH 4
#define TSEQ 2048
#define CHUNK 64
#define NCHUNK (TSEQ / CHUNK)   // 32
#define NTOK (BATCH * TSEQ)     // 8192
#define NBH (BATCH * NHEADS)    // 16
#define EPSV 1e-6f
#define LSTRF 68                // fp32 LDS row stride (verified)
#define PQ 36                   // packed-bf16 LDS row stride in uints (144B)

typedef __bf16 bf16x8 __attribute__((ext_vector_type(8)));
typedef float f32x4 __attribute__((ext_vector_type(4)));
typedef unsigned short us8 __attribute__((ext_vector_type(8)));

__device__ __forceinline__ float elu1(float a) {
    return a > 0.0f ? a + 1.0f : __expf(a);
}

__device__ __forceinline__ unsigned short f2bf(float f) {
    __hip_bfloat16 h = __float2bfloat16(f);   // RNE
    return __builtin_bit_cast(unsigned short, h);
}

__device__ __forceinline__ float bf2f(unsigned short u) {
    return __bfloat162float(__builtin_bit_cast(__hip_bfloat16, u));
}

// unpack a dword holding 2 bf16 (lo,hi) into 2 fp32 — 2 VALU ops
__device__ __forceinline__ void unpack2(unsigned int u, float& lo, float& hi) {
    lo = __builtin_bit_cast(float, u << 16);
    hi = __builtin_bit_cast(float, u & 0xFFFF0000u);
}

// Build a bf16x8 MFMA fragment from 8 consecutive fp32 (16B-aligned).
__device__ __forceinline__ bf16x8 frag8(const float* p) {
    const float4 x = *reinterpret_cast<const float4*>(p);
    const float4 y = *reinterpret_cast<const float4*>(p + 4);
    us8 u;
    u[0] = f2bf(x.x); u[1] = f2bf(x.y); u[2] = f2bf(x.z); u[3] = f2bf(x.w);
    u[4] = f2bf(y.x); u[5] = f2bf(y.y); u[6] = f2bf(y.z); u[7] = f2bf(y.w);
    return __builtin_bit_cast(bf16x8, u);
}

// async global->LDS, 16B per lane; lds ptr must be wave-uniform base.
__device__ __forceinline__ void gld_lds16(const void* g, void* l) {
    __builtin_amdgcn_global_load_lds(
        (const __attribute__((address_space(1))) void*)g,
        (__attribute__((address_space(3))) void*)l, 16, 0, 0);
}

// ---------------------------------------------------------------------------
// fused converts (R12/R16/R17-verified): blocks [0,1024): x->bf16; rest: W^T
// ---------------------------------------------------------------------------
__global__ __launch_bounds__(256) void convert_kernel(
    const float* __restrict__ x,
    const float* __restrict__ Wq, const float* __restrict__ Wk,
    const float* __restrict__ Wv, const float* __restrict__ Wo,
    unsigned short* __restrict__ xb,
    unsigned short* __restrict__ Wt, unsigned short* __restrict__ Wot)
{
    const int tid = threadIdx.x;
    if (blockIdx.x < NTOK * D_MODEL / 8 / 256) {
        const int i = (blockIdx.x * 256 + tid) * 8;
        const float4 a = *reinterpret_cast<const float4*>(&x[i]);
        const float4 b = *reinterpret_cast<const float4*>(&x[i + 4]);
        ushort4 u0 = { f2bf(a.x), f2bf(a.y), f2bf(a.z), f2bf(a.w) };
        ushort4 u1 = { f2bf(b.x), f2bf(b.y), f2bf(b.z), f2bf(b.w) };
        *reinterpret_cast<ushort4*>(&xb[i]) = u0;
        *reinterpret_cast<ushort4*>(&xb[i + 4]) = u1;
        return;
    }
    __shared__ float Ls[64][65];
    const int bid = blockIdx.x - NTOK * D_MODEL / 8 / 256;
    const int wi = bid >> 4;
    const int ti = bid & 15;
    const int k0 = (ti >> 2) * 64, n0 = (ti & 3) * 64;
    const float* W = wi == 0 ? Wq : wi == 1 ? Wk : wi == 2 ? Wv : Wo;
#pragma unroll
    for (int i = 0; i < 16; ++i) {
        const int idx = i * 256 + tid;
        const int r = idx >> 6, c = idx & 63;
        Ls[r][c] = W[(size_t)(k0 + r) * D_MODEL + n0 + c];
    }
    __syncthreads();
    unsigned short* outp = (wi < 3) ? (Wt + (size_t)(wi * 256 + n0) * D_MODEL + k0)
                                    : (Wot + (size_t)n0 * D_MODEL + k0);
#pragma unroll
    for (int i = 0; i < 16; ++i) {
        const int idx = i * 256 + tid;
        const int rn = idx >> 6, ck = idx & 63;
        outp[(size_t)rn * D_MODEL + ck] = f2bf(Ls[ck][rn]);
    }
}

// ---------------------------------------------------------------------------
// FUSED qkv + chunksum: one block per (bh, chunk). Stages x-chunk ONCE
// (full-K, R5-verified gld_lds16+swizzle), runs 3 sequential 64x64 GEMMs
// (Q,K,V) with half-K Bs staging, packs K/V accumulators directly into the
// R17-verified Ktp/Vtp layouts, then runs the verbatim chunksum MFMA + Z.
// All emitted values bit-identical to the R5 pipeline.
// LDS: 32K + 16K + 9K + 9K = 66.5 KB -> 2 blocks/CU.
// ---------------------------------------------------------------------------
__global__ __launch_bounds__(256) void qkvcs_kernel(
    const unsigned short* __restrict__ xb, const unsigned short* __restrict__ Wt,
    const float* __restrict__ bq, const float* __restrict__ bk,
    const float* __restrict__ bv,
    unsigned short* __restrict__ Qb, unsigned short* __restrict__ Kb,
    unsigned short* __restrict__ Vb,
    unsigned short* __restrict__ Pb16, float* __restrict__ Zc)
{
    __shared__ __align__(16) unsigned short As[64 * 256];   // 32 KB, full-K x
    __shared__ __align__(16) unsigned short Bs[64 * 128];   // 16 KB, half-K W
    __shared__ __align__(16) unsigned int Ktp[DHEAD * PQ];  // 9 KB [d][t/2]
    __shared__ __align__(16) unsigned int Vtp[DHEAD * PQ];  // 9 KB [m][t/2]

    const int tid = threadIdx.x;
    const int wave = tid >> 6, lane = tid & 63;
    const int la = lane & 15, q = lane >> 4;
    const int c  = blockIdx.x % NCHUNK;
    const int bh = blockIdx.x / NCHUNK;
    const int b = bh / NHEADS, h = bh % NHEADS;
    const int m0 = b * TSEQ + c * CHUNK;                    // token row base
    const size_t gbase = (size_t)m0 * D_MODEL + h * DHEAD;

    // ---- stage A = x chunk, full-K (verbatim R5 swizzle) ----
    const unsigned short* Ab = xb + (size_t)m0 * D_MODEL;
#pragma unroll
    for (int i = 0; i < 8; ++i) {
        const int bslot = i * 256 + wave * 64;   // wave-uniform base
        const int slot = bslot + lane;
        const int m = slot >> 5, s = slot & 31;
        const int g = s ^ (m & 7);
        gld_lds16(Ab + (size_t)m * D_MODEL + g * 8, &As[bslot * 8]);
    }
    // (first __syncthreads below drains this too)

#pragma unroll
    for (int w = 0; w < 3; ++w) {
        const float* bias = w == 0 ? bq : w == 1 ? bk : bv;
        unsigned short* Out = w == 0 ? Qb : w == 1 ? Kb : Vb;
        const unsigned short* Wb = Wt + (size_t)(w * 256 + h * 64) * D_MODEL;

        f32x4 acc[4];
#pragma unroll
        for (int i = 0; i < 4; ++i) acc[i] = (f32x4){0.f, 0.f, 0.f, 0.f};

#pragma unroll
        for (int half = 0; half < 2; ++half) {
            // stage Bs: rows n in [0,64), k in [half*128, half*128+128)
#pragma unroll
            for (int i = 0; i < 4; ++i) {
                const int bslot = i * 256 + wave * 64;
                const int slot = bslot + lane;           // 0..1023
                const int n = slot >> 4, s = slot & 15;
                const int g = s ^ (n & 7);               // in [0,16)
                gld_lds16(Wb + (size_t)n * D_MODEL + half * 128 + g * 8,
                          &Bs[bslot * 8]);
            }
            __syncthreads();
#pragma unroll
            for (int kh = 0; kh < 4; ++kh) {
                const int glA = half * 16 + kh * 4 + q;  // A k-slot [0,32)
                const int glB = kh * 4 + q;              // B k-slot [0,16)
                const int m = wave * 16 + la;
                const bf16x8 af = *reinterpret_cast<const bf16x8*>(
                    &As[m * 256 + ((glA ^ (m & 7)) << 3)]);
#pragma unroll
                for (int ni = 0; ni < 4; ++ni) {
                    const int n = ni * 16 + la;
                    const bf16x8 bf = *reinterpret_cast<const bf16x8*>(
                        &Bs[n * 128 + ((glB ^ (n & 7)) << 3)]);
                    acc[ni] = __builtin_amdgcn_mfma_f32_16x16x32_bf16(
                        af, bf, acc[ni], 0, 0, 0);
                }
            }
            __syncthreads();
        }

        // ---- epilogue: global write (verbatim class) + K/V LDS pack ----
        // C/D layout: col=lane&15, row=(lane>>4)*4+reg; t = wave*16+q*4+r
#pragma unroll
        for (int ni = 0; ni < 4; ++ni) {
            const int cl = ni * 16 + la;                 // col within head
            const float bv2 = bias[h * 64 + cl];
            float vv[4];
#pragma unroll
            for (int r = 0; r < 4; ++r) {
                float v = acc[ni][r] + bv2;
                if (w < 2) v = elu1(v);
                vv[r] = v;
                const int t = wave * 16 + q * 4 + r;
                Out[gbase + (size_t)t * D_MODEL + cl] = f2bf(v);
            }
            if (w == 1) {      // K -> Ktp[d][t/2], lo = even t
#pragma unroll
                for (int pr = 0; pr < 2; ++pr)
                    Ktp[cl * PQ + wave * 8 + q * 2 + pr] =
                        (unsigned int)f2bf(vv[2 * pr]) |
                        ((unsigned int)f2bf(vv[2 * pr + 1]) << 16);
            } else if (w == 2) {   // V -> Vtp[m][t/2]
#pragma unroll
                for (int pr = 0; pr < 2; ++pr)
                    Vtp[cl * PQ + wave * 8 + q * 2 + pr] =
                        (unsigned int)f2bf(vv[2 * pr]) |
                        ((unsigned int)f2bf(vv[2 * pr + 1]) << 16);
            }
        }
    }
    __syncthreads();

    // ---- chunksum body (verbatim R5): P = V^T K, Z = colsum K ----
    const int wm = (wave >> 1) * 32, wn = (wave & 1) * 32;   // m rows, d cols

    f32x4 pacc[2][2];
#pragma unroll
    for (int i = 0; i < 2; ++i)
#pragma unroll
        for (int j = 0; j < 2; ++j) pacc[i][j] = (f32x4){0.f, 0.f, 0.f, 0.f};

#pragma unroll
    for (int ks = 0; ks < 2; ++ks) {
        const int ku = ks * 16 + q * 4;                      // uint offset (k=t)
        const bf16x8 a0  = __builtin_bit_cast(bf16x8,
            *reinterpret_cast<const uint4*>(&Vtp[(wm + la) * PQ + ku]));
        const bf16x8 a1  = __builtin_bit_cast(bf16x8,
            *reinterpret_cast<const uint4*>(&Vtp[(wm + 16 + la) * PQ + ku]));
        const bf16x8 bb0 = __builtin_bit_cast(bf16x8,
            *reinterpret_cast<const uint4*>(&Ktp[(wn + la) * PQ + ku]));
        const bf16x8 bb1 = __builtin_bit_cast(bf16x8,
            *reinterpret_cast<const uint4*>(&Ktp[(wn + 16 + la) * PQ + ku]));
        pacc[0][0] = __builtin_amdgcn_mfma_f32_16x16x32_bf16(a0, bb0, pacc[0][0], 0, 0, 0);
        pacc[0][1] = __builtin_amdgcn_mfma_f32_16x16x32_bf16(a0, bb1, pacc[0][1], 0, 0, 0);
        pacc[1][0] = __builtin_amdgcn_mfma_f32_16x16x32_bf16(a1, bb0, pacc[1][0], 0, 0, 0);
        pacc[1][1] = __builtin_amdgcn_mfma_f32_16x16x32_bf16(a1, bb1, pacc[1][1], 0, 0, 0);
    }

    unsigned short* Pb = Pb16 + (size_t)blockIdx.x * (DHEAD * DHEAD);
#pragma unroll
    for (int mi = 0; mi < 2; ++mi)
#pragma unroll
        for (int ni = 0; ni < 2; ++ni) {
            const int row = wm + mi * 16 + q * 4;   // m
            const int col = wn + ni * 16 + la;      // d
#pragma unroll
            for (int r = 0; r < 4; ++r)
                Pb[(row + r) * DHEAD + col] = f2bf(pacc[mi][ni][r]);
        }

    if (tid < DHEAD) {
        float z = 0.f;
        for (int tt = 0; tt < 32; ++tt) {
            float lo, hi;
            unpack2(Ktp[tid * PQ + tt], lo, hi);
            z += lo;
            z += hi;
        }
        Zc[(size_t)blockIdx.x * DHEAD + tid] = z;
    }
}

// ---------------------------------------------------------------------------
// prefix — exclusive scan; reads bf16 P, accumulates fp32, emits packed Sb.
// (verbatim R5)
// ---------------------------------------------------------------------------
__global__ __launch_bounds__(256) void prefix_kernel(
    const unsigned short* __restrict__ Pb16, float* __restrict__ Zc,
    unsigned short* __restrict__ Sb)
{
    const int tid = threadIdx.x;
    if (blockIdx.x < NBH * 16) {
        const int bh = blockIdx.x >> 4;
        const int e = ((blockIdx.x & 15) << 8) + tid;
        const size_t base = (size_t)bh * NCHUNK * (DHEAD * DHEAD) + e;
        float v[NCHUNK];
#pragma unroll
        for (int c = 0; c < NCHUNK; ++c)
            v[c] = bf2f(Pb16[base + (size_t)c * (DHEAD * DHEAD)]);
        float s = 0.f;
#pragma unroll
        for (int c = 0; c < NCHUNK; ++c) {
            const float t = v[c];
            Sb[base + (size_t)c * (DHEAD * DHEAD)] = f2bf(s);
            s += t;
        }
    } else {
        const int j = ((int)(blockIdx.x - NBH * 16) << 8) + tid;
        if (j < NBH * DHEAD) {
            const int bh = j >> 6, d = j & 63;
            float v[NCHUNK];
#pragma unroll
            for (int c = 0; c < NCHUNK; ++c) v[c] = Zc[(bh * NCHUNK + c) * DHEAD + d];
            float s = 0.f;
#pragma unroll
            for (int c = 0; c < NCHUNK; ++c) {
                const float t = v[c];
                Zc[(bh * NCHUNK + c) * DHEAD + d] = s;
                s += t;
            }
        }
    }
}

// ---------------------------------------------------------------------------
// chunkout (verbatim R5): packed LDS Q/K/V, Sb B-frags as uint4 from global.
// ---------------------------------------------------------------------------
__global__ __launch_bounds__(256) void chunkout_kernel(
    const unsigned short* __restrict__ Qb, const unsigned short* __restrict__ Kb,
    const unsigned short* __restrict__ Vb,
    const unsigned short* __restrict__ Sb, const float* __restrict__ Zx,
    unsigned short* __restrict__ Ob)
{
    __shared__ __align__(16) unsigned int Qp[CHUNK * PQ];   // packed [t][d/2]
    __shared__ __align__(16) unsigned int Kp[CHUNK * PQ];   // packed [s][d/2]
    __shared__ __align__(16) unsigned int Vtp[DHEAD * PQ];  // packed [m][s/2]
    __shared__ __align__(16) float At[CHUNK * LSTRF];       // fp32 [t][s]
    __shared__ float zsh[DHEAD];
    __shared__ float dnm[CHUNK];

    const int tid = threadIdx.x;
    const int c  = blockIdx.x % NCHUNK;
    const int bh = blockIdx.x / NCHUNK;
    const int b = bh / NHEADS, h = bh % NHEADS;
    const size_t gbase = ((size_t)(b * TSEQ + c * CHUNK)) * D_MODEL + h * DHEAD;
    const unsigned short* Sp = Sb + (size_t)blockIdx.x * (DHEAD * DHEAD);

    // stage Q,K: straight packed 16B copies (no conversion)
#pragma unroll
    for (int i = 0; i < 2; ++i) {
        const int idx = i * 256 + tid;           // 0..511
        const int t = idx >> 3, e4 = (idx & 7) * 4;   // uint offset in row
        const uint4 qv = *reinterpret_cast<const uint4*>(
            &Qb[gbase + (size_t)t * D_MODEL + e4 * 2]);
        const uint4 kv = *reinterpret_cast<const uint4*>(
            &Kb[gbase + (size_t)t * D_MODEL + e4 * 2]);
        *reinterpret_cast<uint4*>(&Qp[t * PQ + e4]) = qv;
        *reinterpret_cast<uint4*>(&Kp[t * PQ + e4]) = kv;
    }
    // stage V transposed, packed along s: thread = (s-pair, 8 m's)
    {
        const int sp = tid & 31, mg = tid >> 5;
        const int m0 = mg * 8;
        const uint4 v0 = *reinterpret_cast<const uint4*>(
            &Vb[gbase + (size_t)(2 * sp) * D_MODEL + m0]);
        const uint4 v1 = *reinterpret_cast<const uint4*>(
            &Vb[gbase + (size_t)(2 * sp + 1) * D_MODEL + m0]);
        const unsigned short* ev = reinterpret_cast<const unsigned short*>(&v0);
        const unsigned short* ov = reinterpret_cast<const unsigned short*>(&v1);
#pragma unroll
        for (int j = 0; j < 8; ++j)
            Vtp[(m0 + j) * PQ + sp] =
                (unsigned int)ev[j] | ((unsigned int)ov[j] << 16);
    }
    if (tid < DHEAD)
        zsh[tid] = Zx[((size_t)bh * NCHUNK + c) * DHEAD + tid];
    __syncthreads();

    const int wave = tid >> 6, lane = tid & 63;
    const int la = lane & 15, q = lane >> 4;
    const int wt = (wave >> 1) * 32, wn = (wave & 1) * 32;

    // phase 1: A = Q K^T
    f32x4 acc[2][2];
#pragma unroll
    for (int i = 0; i < 2; ++i)
#pragma unroll
        for (int j = 0; j < 2; ++j) acc[i][j] = (f32x4){0.f, 0.f, 0.f, 0.f};
#pragma unroll
    for (int ks = 0; ks < 2; ++ks) {
        const int ku = ks * 16 + q * 4;                      // uint offset (k=d)
        const bf16x8 a0  = __builtin_bit_cast(bf16x8,
            *reinterpret_cast<const uint4*>(&Qp[(wt + la) * PQ + ku]));
        const bf16x8 a1  = __builtin_bit_cast(bf16x8,
            *reinterpret_cast<const uint4*>(&Qp[(wt + 16 + la) * PQ + ku]));
        const bf16x8 bb0 = __builtin_bit_cast(bf16x8,
            *reinterpret_cast<const uint4*>(&Kp[(wn + la) * PQ + ku]));
        const bf16x8 bb1 = __builtin_bit_cast(bf16x8,
            *reinterpret_cast<const uint4*>(&Kp[(wn + 16 + la) * PQ + ku]));
        acc[0][0] = __builtin_amdgcn_mfma_f32_16x16x32_bf16(a0, bb0, acc[0][0], 0, 0, 0);
        acc[0][1] = __builtin_amdgcn_mfma_f32_16x16x32_bf16(a0, bb1, acc[0][1], 0, 0, 0);
        acc[1][0] = __builtin_amdgcn_mfma_f32_16x16x32_bf16(a1, bb0, acc[1][0], 0, 0, 0);
        acc[1][1] = __builtin_amdgcn_mfma_f32_16x16x32_bf16(a1, bb1, acc[1][1], 0, 0, 0);
    }
#pragma unroll
    for (int mi = 0; mi < 2; ++mi)
#pragma unroll
        for (int ni = 0; ni < 2; ++ni) {
            const int t0 = wt + mi * 16 + q * 4;
            const int s  = wn + ni * 16 + la;
#pragma unroll
            for (int r = 0; r < 4; ++r)
                At[(t0 + r) * LSTRF + s] = (s <= t0 + r) ? acc[mi][ni][r] : 0.f;
        }
    __syncthreads();

    // phase 2: denom[t] = rowsum(A) + Q . Z_prev + eps  (Q via unpack2)
    if (tid < CHUNK) {
        float dv = 0.f;
        for (int s = 0; s < CHUNK; ++s) dv += At[tid * LSTRF + s];
        for (int dd = 0; dd < 32; ++dd) {
            float lo, hi;
            unpack2(Qp[tid * PQ + dd], lo, hi);
            dv = fmaf(lo, zsh[2 * dd], dv);
            dv = fmaf(hi, zsh[2 * dd + 1], dv);
        }
        dnm[tid] = dv + EPSV;
    }
    __syncthreads();

    // phase 3: O = Q @ S_prev + A @ V
    f32x4 o[2][2];
#pragma unroll
    for (int i = 0; i < 2; ++i)
#pragma unroll
        for (int j = 0; j < 2; ++j) o[i][j] = (f32x4){0.f, 0.f, 0.f, 0.f};
#pragma unroll
    for (int ks = 0; ks < 2; ++ks) {
        const int ku = ks * 16 + q * 4;                      // uint offset (k=d)
        const int ko = ks * 32 + q * 8;                      // elem offset
        const bf16x8 a0  = __builtin_bit_cast(bf16x8,
            *reinterpret_cast<const uint4*>(&Qp[(wt + la) * PQ + ku]));
        const bf16x8 a1  = __builtin_bit_cast(bf16x8,
            *reinterpret_cast<const uint4*>(&Qp[(wt + 16 + la) * PQ + ku]));
        const bf16x8 bb0 = __builtin_bit_cast(bf16x8,
            *reinterpret_cast<const uint4*>(&Sp[(wn + la) * DHEAD + ko]));      // global, packed
        const bf16x8 bb1 = __builtin_bit_cast(bf16x8,
            *reinterpret_cast<const uint4*>(&Sp[(wn + 16 + la) * DHEAD + ko])); // global, packed
        o[0][0] = __builtin_amdgcn_mfma_f32_16x16x32_bf16(a0, bb0, o[0][0], 0, 0, 0);
        o[0][1] = __builtin_amdgcn_mfma_f32_16x16x32_bf16(a0, bb1, o[0][1], 0, 0, 0);
        o[1][0] = __builtin_amdgcn_mfma_f32_16x16x32_bf16(a1, bb0, o[1][0], 0, 0, 0);
        o[1][1] = __builtin_amdgcn_mfma_f32_16x16x32_bf16(a1, bb1, o[1][1], 0, 0, 0);
    }
#pragma unroll
    for (int ks = 0; ks < 2; ++ks) {
        const int ku = ks * 16 + q * 4;                      // uint offset (k=s)
        const int ko = ks * 32 + q * 8;
        const bf16x8 a0  = frag8(&At[(wt + la) * LSTRF + ko]);
        const bf16x8 a1  = frag8(&At[(wt + 16 + la) * LSTRF + ko]);
        const bf16x8 bb0 = __builtin_bit_cast(bf16x8,
            *reinterpret_cast<const uint4*>(&Vtp[(wn + la) * PQ + ku]));
        const bf16x8 bb1 = __builtin_bit_cast(bf16x8,
            *reinterpret_cast<const uint4*>(&Vtp[(wn + 16 + la) * PQ + ku]));
        o[0][0] = __builtin_amdgcn_mfma_f32_16x16x32_bf16(a0, bb0, o[0][0], 0, 0, 0);
        o[0][1] = __builtin_amdgcn_mfma_f32_16x16x32_bf16(a0, bb1, o[0][1], 0, 0, 0);
        o[1][0] = __builtin_amdgcn_mfma_f32_16x16x32_bf16(a1, bb0, o[1][0], 0, 0, 0);
        o[1][1] = __builtin_amdgcn_mfma_f32_16x16x32_bf16(a1, bb1, o[1][1], 0, 0, 0);
    }

    // epilogue: divide + bf16 scalar stores (verified class)
#pragma unroll
    for (int mi = 0; mi < 2; ++mi)
#pragma unroll
        for (int ni = 0; ni < 2; ++ni) {
            const int t0 = wt + mi * 16 + q * 4;
            const int m  = wn + ni * 16 + la;
#pragma unroll
            for (int r = 0; r < 4; ++r) {
                const float v = o[mi][ni][r] / dnm[t0 + r];
                Ob[gbase + (size_t)(t0 + r) * D_MODEL + m] = f2bf(v);
            }
        }
}

// ---------------------------------------------------------------------------
// output GEMM (verbatim R5 MODE-1 full-K): A=Ob bf16 via gld_lds16, B=Wot.
// ---------------------------------------------------------------------------
__global__ __launch_bounds__(256) void ogemm_kernel(
    const unsigned short* __restrict__ A,
    const unsigned short* __restrict__ Bt,
    const float* __restrict__ b0, float* __restrict__ out)
{
    __shared__ __align__(16) unsigned short As[64 * 256];   // 32 KB
    __shared__ __align__(16) unsigned short Bs[64 * 256];   // 32 KB
    const int tid = threadIdx.x;
    const int wave = tid >> 6, lane = tid & 63;
    const int la = lane & 15, q = lane >> 4;

    const int ntile = blockIdx.x & 3, mtile = blockIdx.x >> 2;
    const int m0 = mtile * 64, n0 = ntile * 64;

    const unsigned short* Ab = A  + (size_t)m0 * D_MODEL;
    const unsigned short* Bb = Bt + (size_t)n0 * D_MODEL;

#pragma unroll
    for (int i = 0; i < 8; ++i) {
        const int bslot = i * 256 + wave * 64;   // wave-uniform base
        const int slot = bslot + lane;
        const int m = slot >> 5, s = slot & 31;
        const int g = s ^ (m & 7);
        gld_lds16(Ab + (size_t)m * D_MODEL + g * 8, &As[bslot * 8]);
        gld_lds16(Bb + (size_t)m * D_MODEL + g * 8, &Bs[bslot * 8]);
    }
    __syncthreads();

    f32x4 acc[4];
#pragma unroll
    for (int i = 0; i < 4; ++i) acc[i] = (f32x4){0.f, 0.f, 0.f, 0.f};

#pragma unroll
    for (int kh = 0; kh < 8; ++kh) {
        const int gl = kh * 4 + q;
        const int m = wave * 16 + la;
        const bf16x8 af = *reinterpret_cast<const bf16x8*>(
            &As[m * 256 + ((gl ^ (m & 7)) << 3)]);
#pragma unroll
        for (int ni = 0; ni < 4; ++ni) {
            const int n = ni * 16 + la;
            const bf16x8 bf = *reinterpret_cast<const bf16x8*>(
                &Bs[n * 256 + ((gl ^ (n & 7)) << 3)]);
            acc[ni] = __builtin_amdgcn_mfma_f32_16x16x32_bf16(
                af, bf, acc[ni], 0, 0, 0);
        }
    }

#pragma unroll
    for (int ni = 0; ni < 4; ++ni) {
        const int row = m0 + wave * 16 + q * 4;
        const int col = n0 + ni * 16 + la;
        const float bv2 = b0[col];
#pragma unroll
        for (int r = 0; r < 4; ++r)
            out[(size_t)(row + r) * D_MODEL + col] = acc[ni][r] + bv2;
    }
}

extern "C" void kernel_launch(void* const* d_in, const int* in_sizes, int n_in,
                              void* d_out, int out_size, void* d_ws, size_t ws_size,
                              hipStream_t stream)
{
    const float* x  = (const float*)d_in[0];
    const float* Wq = (const float*)d_in[1];
    const float* bq = (const float*)d_in[2];
    const float* Wk = (const float*)d_in[3];
    const float* bk = (const float*)d_in[4];
    const float* Wv = (const float*)d_in[5];
    const float* bv = (const float*)d_in[6];
    const float* Wo = (const float*)d_in[7];
    const float* bo = (const float*)d_in[8];
    float* out = (float*)d_out;

    const size_t NE = (size_t)NTOK * D_MODEL;               // 2M elems
    const size_t PE = (size_t)NBH * NCHUNK * DHEAD * DHEAD; // 2M elems
    unsigned short* xb   = (unsigned short*)d_ws;           // 2M bf16
    unsigned short* Wt   = xb + NE;                         // 768*256
    unsigned short* Wot  = Wt + 768 * 256;                  // 256*256
    unsigned short* Qb   = Wot + 256 * 256;                 // 2M
    unsigned short* Kb   = Qb + NE;                         // 2M
    unsigned short* Vb   = Kb + NE;                         // 2M
    unsigned short* Ob   = Vb + NE;                         // 2M
    unsigned short* Sb   = Ob + NE;                         // 2M bf16
    unsigned short* Pb16 = Sb + PE;                         // 2M bf16
    float* Z = (float*)(Pb16 + PE);                         // 16*32*64 f32

    convert_kernel<<<NTOK * D_MODEL / 8 / 256 + 64, 256, 0, stream>>>(
        x, Wq, Wk, Wv, Wo, xb, Wt, Wot);
    qkvcs_kernel<<<NBH * NCHUNK, 256, 0, stream>>>(
        xb, Wt, bq, bk, bv, Qb, Kb, Vb, Pb16, Z);
    prefix_kernel<<<NBH * 16 + 4, 256, 0, stream>>>(Pb16, Z, Sb);
    chunkout_kernel<<<NBH * NCHUNK, 256, 0, stream>>>(Qb, Kb, Vb, Sb, Z, Ob);
    ogemm_kernel<<<(NTOK / 64) * 4, 256, 0, stream>>>(Ob, Wot, bo, out);
}